// Round 5
// baseline (944.674 us; speedup 1.0000x reference)
//
#include <hip/hip_runtime.h>

#define NPTS   300000
#define NPAIRS 100000
#define KOFF   27
#define CIN    32
#define COUT   64
#define NGROUP 8
#define EPSV   1e-5f
#define SLOPE  0.01f

#define PAIRS_PER_BLOCK 256
#define BLOCKS_PER_K ((NPAIRS + PAIRS_PER_BLOCK - 1) / PAIRS_PER_BLOCK)  // 391

// ---------------------------------------------------------------- zero
__global__ __launch_bounds__(256) void zero_kernel(float4* __restrict__ out4, int n4,
                                                   float* __restrict__ stats) {
    int i = blockIdx.x * blockDim.x + threadIdx.x;
    if (i < n4) out4[i] = make_float4(0.f, 0.f, 0.f, 0.f);
    if (blockIdx.x == 0 && threadIdx.x < 16) stats[threadIdx.x] = 0.f;
}

// ---------------------------------------------------------------- conv (gather-matmul-scatter)
// lane = output channel c; one wave streams 64 pairs of one kernel offset k.
// KEY CHANGE (round 5): the feats-row gather goes through the VECTOR memory
// pipe, not the scalar pipe. Rounds 0/1/4 all used wave-uniform s_load rows
// (readfirstlane) and all hit the same 569us wall regardless of VALU pressure,
// register allocation, or pipelining: SMEM has tiny shared K$ + few MSHRs and
// its OOO returns force lgkmcnt(0) drains. Here:
//   - the wave's 64 pair indices are ONE coalesced vector load, shfl-broadcast
//   - each row = 8x global_load_dwordx4 of a uniform VGPR address (one 128B
//     line, HW broadcast), counted on vmcnt -> deep MLP
//   - depth-2 A/B register tiles (all statically indexed) hide the line fill
//     of pair j+2 under pair j's FMAs.
__global__ __launch_bounds__(256) void conv_kernel(
    const float* __restrict__ feats, const float* __restrict__ weight,
    const int* __restrict__ in_idx, const int* __restrict__ out_idx,
    float* __restrict__ out)
{
    const int lane = threadIdx.x & 63;
    const int wave = threadIdx.x >> 6;
    const int k     = blockIdx.x / BLOCKS_PER_K;
    const int pair0 = (blockIdx.x % BLOCKS_PER_K) * PAIRS_PER_BLOCK;

    const int p0 = pair0 + wave * 64;
    if (p0 >= NPAIRS) return;
    int n = NPAIRS - p0; if (n > 64) n = 64;

    // per-lane weight column W[k][:,lane], loaded once (coalesced)
    float w[CIN];
    const float* wk = weight + k * (CIN * COUT) + lane;
#pragma unroll
    for (int i = 0; i < CIN; ++i) w[i] = wk[i * COUT];

    // wave's 64 pair indices: one coalesced vector load each
    const int* ii = in_idx  + k * NPAIRS;
    const int* oi = out_idx + k * NPAIRS;
    int pidx = p0 + lane; if (pidx >= NPAIRS) pidx = NPAIRS - 1;
    const int rinv  = ii[pidx];
    const int routv = oi[pidx];

    float4 A[8], B[8];                       // two row tiles (ping-pong, static idx)

    auto loadrow = [&](int j, float4* R) {
        int r = __shfl(rinv, j, 64);         // broadcast, no memory op
        const float4* fr = (const float4*)(feats + (size_t)r * CIN);
#pragma unroll
        for (int q = 0; q < 8; ++q) R[q] = fr[q];   // uniform-addr vector loads
    };
    auto compute = [&](const float4* R, int j) {
        int rout = __shfl(routv, j, 64);
        float a0 = 0.f, a1 = 0.f, a2 = 0.f, a3 = 0.f;
#pragma unroll
        for (int q = 0; q < 8; ++q) {
            a0 = fmaf(R[q].x, w[4 * q + 0], a0);
            a1 = fmaf(R[q].y, w[4 * q + 1], a1);
            a2 = fmaf(R[q].z, w[4 * q + 2], a2);
            a3 = fmaf(R[q].w, w[4 * q + 3], a3);
        }
        atomicAdd(out + (size_t)rout * COUT + lane, (a0 + a1) + (a2 + a3));
    };

    loadrow(0, A);
    if (n > 1) loadrow(1, B);
    int j = 0;
    while (true) {
        compute(A, j);
        if (j + 2 < n) loadrow(j + 2, A);    // prefetch 2 ahead into the tile just freed
        ++j; if (j >= n) break;
        compute(B, j);
        if (j + 2 < n) loadrow(j + 2, B);
        ++j; if (j >= n) break;
    }
}

// ---------------------------------------------------------------- group stats (sum, sumsq)
// float4 per thread; channel block (i&15)*4 constant per thread (grid stride
// multiple of 16). Wave shuffle-reduce -> LDS -> 16 atomics per block.
__global__ __launch_bounds__(256) void stats_kernel(const float4* __restrict__ out4,
                                                    float* __restrict__ stats) {
    const int tid  = blockIdx.x * 256 + threadIdx.x;
    const int ntid = gridDim.x * 256;                 // multiple of 16
    const int n4   = NPTS * COUT / 4;

    float s = 0.f, ss = 0.f;
    for (int i = tid; i < n4; i += ntid) {
        float4 v = out4[i];
        s  += v.x + v.y + v.z + v.w;
        ss += v.x * v.x + v.y * v.y + v.z * v.z + v.w * v.w;
    }
    // group of this thread's float4: g = (lane&15)>>1, same for lanes l^1, l^16, l^32
    s  += __shfl_xor(s,  1, 64);  ss += __shfl_xor(ss,  1, 64);
    s  += __shfl_xor(s, 16, 64);  ss += __shfl_xor(ss, 16, 64);
    s  += __shfl_xor(s, 32, 64);  ss += __shfl_xor(ss, 32, 64);

    __shared__ float sm_s[4][NGROUP];
    __shared__ float sm_ss[4][NGROUP];
    const int lane = threadIdx.x & 63;
    const int wv   = threadIdx.x >> 6;
    if (lane < 16 && (lane & 1) == 0) {
        sm_s [wv][lane >> 1] = s;
        sm_ss[wv][lane >> 1] = ss;
    }
    __syncthreads();
    if (threadIdx.x < NGROUP) {
        float ts = 0.f, tss = 0.f;
#pragma unroll
        for (int wvi = 0; wvi < 4; ++wvi) { ts += sm_s[wvi][threadIdx.x]; tss += sm_ss[wvi][threadIdx.x]; }
        atomicAdd(stats + threadIdx.x,          ts);
        atomicAdd(stats + NGROUP + threadIdx.x, tss);
    }
}

// ---------------------------------------------------------------- normalize + affine + leaky relu
__global__ __launch_bounds__(256) void norm_kernel(float4* __restrict__ out4, int n4,
                                                   const float* __restrict__ stats,
                                                   const float* __restrict__ gamma,
                                                   const float* __restrict__ beta) {
    int i = blockIdx.x * blockDim.x + threadIdx.x;
    if (i >= n4) return;
    int c0 = (i & 15) * 4;              // first channel of this float4; stays in one group
    int g  = c0 >> 3;
    const float cnt = (float)NPTS * (COUT / NGROUP);
    float mean = stats[g] / cnt;
    float var  = stats[8 + g] / cnt - mean * mean;
    float inv  = rsqrtf(var + EPSV);
    float4 v  = out4[i];
    float4 ga = *(const float4*)(gamma + c0);
    float4 be = *(const float4*)(beta  + c0);
    float x;
    x = (v.x - mean) * inv * ga.x + be.x; v.x = x >= 0.f ? x : SLOPE * x;
    x = (v.y - mean) * inv * ga.y + be.y; v.y = x >= 0.f ? x : SLOPE * x;
    x = (v.z - mean) * inv * ga.z + be.z; v.z = x >= 0.f ? x : SLOPE * x;
    x = (v.w - mean) * inv * ga.w + be.w; v.w = x >= 0.f ? x : SLOPE * x;
    out4[i] = v;
}

// ---------------------------------------------------------------- launch
extern "C" void kernel_launch(void* const* d_in, const int* in_sizes, int n_in,
                              void* d_out, int out_size, void* d_ws, size_t ws_size,
                              hipStream_t stream) {
    const float* feats  = (const float*)d_in[0];
    const float* weight = (const float*)d_in[1];
    const float* gamma  = (const float*)d_in[2];
    const float* beta   = (const float*)d_in[3];
    const int*   in_idx = (const int*)d_in[4];
    const int*   out_idx= (const int*)d_in[5];
    float* out   = (float*)d_out;
    float* stats = (float*)d_ws;

    int n4 = out_size / 4;                 // 4.8M float4
    int zb = (n4 + 255) / 256;

    zero_kernel<<<zb, 256, 0, stream>>>((float4*)out, n4, stats);
    conv_kernel<<<KOFF * BLOCKS_PER_K, 256, 0, stream>>>(feats, weight, in_idx, out_idx, out);
    stats_kernel<<<2048, 256, 0, stream>>>((const float4*)out, stats);
    norm_kernel<<<zb, 256, 0, stream>>>((float4*)out, n4, stats, gamma, beta);
}

// Round 6
// 743.250 us; speedup vs baseline: 1.2710x; 1.2710x over previous
//
#include <hip/hip_runtime.h>

#define NPTS   300000
#define NPAIRS 100000
#define KOFF   27
#define CIN    32
#define COUT   64
#define NGROUP 8
#define EPSV   1e-5f
#define SLOPE  0.01f

#define PAIRS_PER_BLOCK 256
#define BLOCKS_PER_K ((NPAIRS + PAIRS_PER_BLOCK - 1) / PAIRS_PER_BLOCK)  // 391

// ---------------------------------------------------------------- zero
__global__ __launch_bounds__(256) void zero_kernel(float4* __restrict__ out4, int n4,
                                                   float* __restrict__ stats) {
    int i = blockIdx.x * blockDim.x + threadIdx.x;
    if (i < n4) out4[i] = make_float4(0.f, 0.f, 0.f, 0.f);
    if (blockIdx.x == 0 && threadIdx.x < 16) stats[threadIdx.x] = 0.f;
}

// ---------------------------------------------------------------- conv (gather-matmul-scatter)
// ROUND 6: memory-level parallelism moved from the wave to the LANES.
// Six prior datapoints show any wave-serial per-pair row fetch (scalar s_load
// or uniform vector load, any pipelining depth) is latency-bound at >=569us:
// a wave can keep only O(2) rows in flight. Here:
//   Phase A: lane = pair. Each lane gathers its own pair's 128B feats row
//            (8x global_load_dwordx4, per-lane addresses) -> 512 independent
//            loads in flight per wave -> latency amortized 64x. Rows land in
//            a wave-private LDS slice (144B stride, 16B aligned, no barrier:
//            same-wave DS ordering + compiler lgkmcnt suffice).
//   Phase B: proven round-0 compute. Wave per pair, lane = channel, W[k][:,c]
//            in 32 VGPRs; row read as 8 uniform-address ds_read_b128
//            (hardware broadcast, conflict-free) instead of a ~600cyc random
//            global load. Coalesced 256B wave-atomic scatter unchanged.
__global__ __launch_bounds__(256) void conv_kernel(
    const float* __restrict__ feats, const float* __restrict__ weight,
    const int* __restrict__ in_idx, const int* __restrict__ out_idx,
    float* __restrict__ out)
{
    __shared__ float rows[4][64][36];          // 36 floats = 144B row stride; 36KB/block
    const int lane = threadIdx.x & 63;
    const int wv   = threadIdx.x >> 6;
    const int k     = blockIdx.x / BLOCKS_PER_K;
    const int pair0 = (blockIdx.x % BLOCKS_PER_K) * PAIRS_PER_BLOCK + wv * 64;
    if (pair0 >= NPAIRS) return;
    int n = NPAIRS - pair0; if (n > 64) n = 64;

    // per-lane weight column W[k][:,lane] (coalesced, loaded once)
    float w[CIN];
    const float* wk = weight + k * (CIN * COUT) + lane;
#pragma unroll
    for (int i = 0; i < CIN; ++i) w[i] = wk[i * COUT];

    const int* ii = in_idx  + k * NPAIRS;
    const int* oi = out_idx + k * NPAIRS;

    const int myp   = pair0 + ((lane < n) ? lane : (n - 1));
    const int routv = oi[myp];                 // scatter row, shfl-broadcast later

    // ---- phase A: per-lane gather, 8 outstanding 16B loads per lane ----
    if (lane < n) {
        const int rin = ii[myp];
        const float4* fr = (const float4*)(feats + (size_t)rin * CIN);
        float4* dst = (float4*)&rows[wv][lane][0];
#pragma unroll
        for (int q = 0; q < 8; ++q) dst[q] = fr[q];
    }

    // ---- phase B: wave per pair, row broadcast from LDS ----
    for (int j = 0; j < n; ++j) {
        const int rout = __shfl(routv, j, 64);             // no memory op
        const float4* fr4 = (const float4*)&rows[wv][j][0];
        float4 r0 = fr4[0], r1 = fr4[1], r2 = fr4[2], r3 = fr4[3];
        float4 r4 = fr4[4], r5 = fr4[5], r6 = fr4[6], r7 = fr4[7];
        float a0 = 0.f, a1 = 0.f, a2 = 0.f, a3 = 0.f;
        a0 = fmaf(r0.x, w[0],  a0); a1 = fmaf(r0.y, w[1],  a1);
        a2 = fmaf(r0.z, w[2],  a2); a3 = fmaf(r0.w, w[3],  a3);
        a0 = fmaf(r1.x, w[4],  a0); a1 = fmaf(r1.y, w[5],  a1);
        a2 = fmaf(r1.z, w[6],  a2); a3 = fmaf(r1.w, w[7],  a3);
        a0 = fmaf(r2.x, w[8],  a0); a1 = fmaf(r2.y, w[9],  a1);
        a2 = fmaf(r2.z, w[10], a2); a3 = fmaf(r2.w, w[11], a3);
        a0 = fmaf(r3.x, w[12], a0); a1 = fmaf(r3.y, w[13], a1);
        a2 = fmaf(r3.z, w[14], a2); a3 = fmaf(r3.w, w[15], a3);
        a0 = fmaf(r4.x, w[16], a0); a1 = fmaf(r4.y, w[17], a1);
        a2 = fmaf(r4.z, w[18], a2); a3 = fmaf(r4.w, w[19], a3);
        a0 = fmaf(r5.x, w[20], a0); a1 = fmaf(r5.y, w[21], a1);
        a2 = fmaf(r5.z, w[22], a2); a3 = fmaf(r5.w, w[23], a3);
        a0 = fmaf(r6.x, w[24], a0); a1 = fmaf(r6.y, w[25], a1);
        a2 = fmaf(r6.z, w[26], a2); a3 = fmaf(r6.w, w[27], a3);
        a0 = fmaf(r7.x, w[28], a0); a1 = fmaf(r7.y, w[29], a1);
        a2 = fmaf(r7.z, w[30], a2); a3 = fmaf(r7.w, w[31], a3);
        atomicAdd(out + (size_t)rout * COUT + lane, (a0 + a1) + (a2 + a3));
    }
}

// ---------------------------------------------------------------- group stats (sum, sumsq)
__global__ __launch_bounds__(256) void stats_kernel(const float4* __restrict__ out4,
                                                    float* __restrict__ stats) {
    const int tid  = blockIdx.x * 256 + threadIdx.x;
    const int ntid = gridDim.x * 256;                 // multiple of 16
    const int n4   = NPTS * COUT / 4;

    float s = 0.f, ss = 0.f;
    for (int i = tid; i < n4; i += ntid) {
        float4 v = out4[i];
        s  += v.x + v.y + v.z + v.w;
        ss += v.x * v.x + v.y * v.y + v.z * v.z + v.w * v.w;
    }
    // group of this thread's float4: g = (lane&15)>>1, same for lanes l^1, l^16, l^32
    s  += __shfl_xor(s,  1, 64);  ss += __shfl_xor(ss,  1, 64);
    s  += __shfl_xor(s, 16, 64);  ss += __shfl_xor(ss, 16, 64);
    s  += __shfl_xor(s, 32, 64);  ss += __shfl_xor(ss, 32, 64);

    __shared__ float sm_s[4][NGROUP];
    __shared__ float sm_ss[4][NGROUP];
    const int lane = threadIdx.x & 63;
    const int wv   = threadIdx.x >> 6;
    if (lane < 16 && (lane & 1) == 0) {
        sm_s [wv][lane >> 1] = s;
        sm_ss[wv][lane >> 1] = ss;
    }
    __syncthreads();
    if (threadIdx.x < NGROUP) {
        float ts = 0.f, tss = 0.f;
#pragma unroll
        for (int wvi = 0; wvi < 4; ++wvi) { ts += sm_s[wvi][threadIdx.x]; tss += sm_ss[wvi][threadIdx.x]; }
        atomicAdd(stats + threadIdx.x,          ts);
        atomicAdd(stats + NGROUP + threadIdx.x, tss);
    }
}

// ---------------------------------------------------------------- normalize + affine + leaky relu
__global__ __launch_bounds__(256) void norm_kernel(float4* __restrict__ out4, int n4,
                                                   const float* __restrict__ stats,
                                                   const float* __restrict__ gamma,
                                                   const float* __restrict__ beta) {
    int i = blockIdx.x * blockDim.x + threadIdx.x;
    if (i >= n4) return;
    int c0 = (i & 15) * 4;              // first channel of this float4; stays in one group
    int g  = c0 >> 3;
    const float cnt = (float)NPTS * (COUT / NGROUP);
    float mean = stats[g] / cnt;
    float var  = stats[8 + g] / cnt - mean * mean;
    float inv  = rsqrtf(var + EPSV);
    float4 v  = out4[i];
    float4 ga = *(const float4*)(gamma + c0);
    float4 be = *(const float4*)(beta  + c0);
    float x;
    x = (v.x - mean) * inv * ga.x + be.x; v.x = x >= 0.f ? x : SLOPE * x;
    x = (v.y - mean) * inv * ga.y + be.y; v.y = x >= 0.f ? x : SLOPE * x;
    x = (v.z - mean) * inv * ga.z + be.z; v.z = x >= 0.f ? x : SLOPE * x;
    x = (v.w - mean) * inv * ga.w + be.w; v.w = x >= 0.f ? x : SLOPE * x;
    out4[i] = v;
}

// ---------------------------------------------------------------- launch
extern "C" void kernel_launch(void* const* d_in, const int* in_sizes, int n_in,
                              void* d_out, int out_size, void* d_ws, size_t ws_size,
                              hipStream_t stream) {
    const float* feats  = (const float*)d_in[0];
    const float* weight = (const float*)d_in[1];
    const float* gamma  = (const float*)d_in[2];
    const float* beta   = (const float*)d_in[3];
    const int*   in_idx = (const int*)d_in[4];
    const int*   out_idx= (const int*)d_in[5];
    float* out   = (float*)d_out;
    float* stats = (float*)d_ws;

    int n4 = out_size / 4;                 // 4.8M float4
    int zb = (n4 + 255) / 256;

    zero_kernel<<<zb, 256, 0, stream>>>((float4*)out, n4, stats);
    conv_kernel<<<KOFF * BLOCKS_PER_K, 256, 0, stream>>>(feats, weight, in_idx, out_idx, out);
    stats_kernel<<<2048, 256, 0, stream>>>((const float4*)out, stats);
    norm_kernel<<<zb, 256, 0, stream>>>((float4*)out, n4, stats, gamma, beta);
}